// Round 1
// baseline (5562.733 us; speedup 1.0000x reference)
//
#include <hip/hip_runtime.h>

#define HH 256
#define WW 256
#define BATCH 4
#define NCC 64
#define EPS 1e-5f
#define SELU_L 1.0507009873554805f
#define SELU_A 1.6732632423543772f

__device__ __forceinline__ float selu_f(float x) {
    return x > 0.f ? SELU_L * x : SELU_L * SELU_A * (__expf(x) - 1.f);
}

// ---------------- conv_in: 3 -> 64, BN, SELU ----------------
__global__ __launch_bounds__(256) void k_conv_in(
    const float* __restrict__ X, const float* __restrict__ w,
    const float* __restrict__ bconv, const float* __restrict__ g,
    const float* __restrict__ be, const float* __restrict__ m,
    const float* __restrict__ v, float* __restrict__ out)
{
    __shared__ float s_x[3][18][18];
    __shared__ float s_w[64][28];   // 27 used, row = 112B (16B aligned)
    __shared__ float s_sc[64], s_bs[64];
    const int tid = threadIdx.x;
    const int w0 = blockIdx.x * 16, h0 = blockIdx.y * 16, b = blockIdx.z;

    for (int idx = tid; idx < 3 * 324; idx += 256) {
        int ci = idx / 324, rem = idx - ci * 324;
        int r = rem / 18, c = rem - r * 18;
        int gh = h0 - 1 + r, gw = w0 - 1 + c;
        float val = 0.f;
        if ((unsigned)gh < HH && (unsigned)gw < WW)
            val = X[((b * 3 + ci) << 16) + (gh << 8) + gw];
        s_x[ci][r][c] = val;
    }
    for (int e = tid; e < 64 * 27; e += 256) {
        int co = e / 27, t = e - co * 27;
        s_w[co][t] = w[e];
    }
    if (tid < 64) {
        float sc = g[tid] * rsqrtf(v[tid] + EPS);
        s_sc[tid] = sc;
        s_bs[tid] = (bconv[tid] - m[tid]) * sc + be[tid];
    }
    __syncthreads();

    const int r = tid >> 4, c = tid & 15;
    float xv[3][3][3];
    #pragma unroll
    for (int ci = 0; ci < 3; ++ci)
        #pragma unroll
        for (int kh = 0; kh < 3; ++kh)
            #pragma unroll
            for (int kw = 0; kw < 3; ++kw)
                xv[ci][kh][kw] = s_x[ci][r + kh][c + kw];

    const int h = h0 + r, wc = w0 + c;
    for (int co = 0; co < 64; ++co) {
        float acc = 0.f;
        #pragma unroll
        for (int ci = 0; ci < 3; ++ci)
            #pragma unroll
            for (int kh = 0; kh < 3; ++kh)
                #pragma unroll
                for (int kw = 0; kw < 3; ++kw)
                    acc = fmaf(xv[ci][kh][kw], s_w[co][ci * 9 + kh * 3 + kw], acc);
        float val = selu_f(acc * s_sc[co] + s_bs[co]);
        out[((b * NCC + co) << 16) + (h << 8) + wc] = val;
    }
}

// ---------------- hidden: 64 -> 64, BN, SELU (the hot kernel) ----------------
// Block: 256 threads = 4 co-groups (wave-uniform) x 64 pixel-threads.
// Each thread: 16 out-channels x 4 pixels = 64 fp32 accumulators.
// Per (ci,kh,kw): 16 weights (wave-uniform LDS broadcast, 4x ds_read_b128)
//                + 4 xv (per-lane b32) feed 64 v_fmac_f32 -> VALU-bound.
__global__ __launch_bounds__(256) void k_hidden(
    const float* __restrict__ in, const float* __restrict__ wh,
    const float* __restrict__ bconv, const float* __restrict__ g,
    const float* __restrict__ be, const float* __restrict__ m,
    const float* __restrict__ v, float* __restrict__ out)
{
    __shared__ float s_in[16][18][18];   // 20.7 KB
    __shared__ float s_w[144][64];       // 36.9 KB  (k-major, co contiguous)
    const int tid = threadIdx.x;
    const int w0 = blockIdx.x * 16, h0 = blockIdx.y * 16, b = blockIdx.z;
    const int co_base = (tid >> 6) << 4;   // 0,16,32,48 — uniform per wave
    const int pix = tid & 63;
    const int r0 = pix >> 4;               // 0..3
    const int col = pix & 15;

    float acc[4][16];
    #pragma unroll
    for (int k = 0; k < 4; ++k)
        #pragma unroll
        for (int j = 0; j < 16; ++j) acc[k][j] = 0.f;

    for (int cc = 0; cc < 4; ++cc) {
        const int ci0 = cc << 4;
        // stage input tile (16 ci x 18 x 18, zero-padded at image borders)
        for (int idx = tid; idx < 16 * 324; idx += 256) {
            int ci = idx / 324, rem = idx - ci * 324;
            int rr = rem / 18, c2 = rem - rr * 18;
            int gh = h0 - 1 + rr, gw = w0 - 1 + c2;
            float val = 0.f;
            if ((unsigned)gh < HH && (unsigned)gw < WW)
                val = in[((b * NCC + ci0 + ci) << 16) + (gh << 8) + gw];
            s_in[ci][rr][c2] = val;
        }
        // stage weights: s_w[kidx][co] = wh[co*576 + ci0*9 + kidx]
        // (scattered global reads hit L1/L2 — weights are 147 KB total)
        for (int e = tid; e < 144 * 64; e += 256) {
            int kidx = e >> 6, co = e & 63;
            s_w[kidx][co] = wh[co * 576 + ci0 * 9 + kidx];
        }
        __syncthreads();

        for (int ci = 0; ci < 16; ++ci) {
            #pragma unroll
            for (int kh = 0; kh < 3; ++kh) {
                #pragma unroll
                for (int kw = 0; kw < 3; ++kw) {
                    float wv[16];
                    #pragma unroll
                    for (int j = 0; j < 16; ++j)
                        wv[j] = s_w[ci * 9 + kh * 3 + kw][co_base + j];
                    #pragma unroll
                    for (int k = 0; k < 4; ++k) {
                        float xv = s_in[ci][r0 + 4 * k + kh][col + kw];
                        #pragma unroll
                        for (int j = 0; j < 16; ++j)
                            acc[k][j] = fmaf(xv, wv[j], acc[k][j]);
                    }
                }
            }
        }
        __syncthreads();
    }

    // epilogue: BN fold + SELU + store
    #pragma unroll
    for (int j = 0; j < 16; ++j) {
        int co = co_base + j;
        float sc = g[co] * rsqrtf(v[co] + EPS);
        float bs = (bconv[co] - m[co]) * sc + be[co];
        #pragma unroll
        for (int k = 0; k < 4; ++k) {
            float val = selu_f(acc[k][j] * sc + bs);
            out[((b * NCC + co) << 16) + ((h0 + r0 + 4 * k) << 8) + (w0 + col)] = val;
        }
    }
}

// ---------------- conv_out: 64 -> 3, BN, SELU, + interpolate_zeros(X) ----------------
__global__ __launch_bounds__(256) void k_conv_out(
    const float* __restrict__ in, const float* __restrict__ wo,
    const float* __restrict__ bconv, const float* __restrict__ g,
    const float* __restrict__ be, const float* __restrict__ m,
    const float* __restrict__ v, const float* __restrict__ X,
    float* __restrict__ out)
{
    __shared__ float s_in[16][18][18];
    __shared__ float s_w[3][576];
    const int tid = threadIdx.x;
    const int w0 = blockIdx.x * 16, h0 = blockIdx.y * 16, b = blockIdx.z;

    for (int e = tid; e < 3 * 576; e += 256)
        s_w[e / 576][e % 576] = wo[e];

    float acc0 = 0.f, acc1 = 0.f, acc2 = 0.f;
    const int r = tid >> 4, c = tid & 15;

    for (int cc = 0; cc < 4; ++cc) {
        const int ci0 = cc << 4;
        for (int idx = tid; idx < 16 * 324; idx += 256) {
            int ci = idx / 324, rem = idx - ci * 324;
            int rr = rem / 18, c2 = rem - rr * 18;
            int gh = h0 - 1 + rr, gw = w0 - 1 + c2;
            float val = 0.f;
            if ((unsigned)gh < HH && (unsigned)gw < WW)
                val = in[((b * NCC + ci0 + ci) << 16) + (gh << 8) + gw];
            s_in[ci][rr][c2] = val;
        }
        __syncthreads();
        for (int ci = 0; ci < 16; ++ci) {
            #pragma unroll
            for (int kh = 0; kh < 3; ++kh) {
                #pragma unroll
                for (int kw = 0; kw < 3; ++kw) {
                    float xv = s_in[ci][r + kh][c + kw];
                    int kk = (ci0 + ci) * 9 + kh * 3 + kw;
                    acc0 = fmaf(xv, s_w[0][kk], acc0);
                    acc1 = fmaf(xv, s_w[1][kk], acc1);
                    acc2 = fmaf(xv, s_w[2][kk], acc2);
                }
            }
        }
        __syncthreads();
    }

    const int h = h0 + r, wc = w0 + c;
    float accs[3] = {acc0, acc1, acc2};
    #pragma unroll
    for (int co = 0; co < 3; ++co) {
        float sc = g[co] * rsqrtf(v[co] + EPS);
        float bs = (bconv[co] - m[co]) * sc + be[co];
        float val = selu_f(accs[co] * sc + bs);
        const float* Xc = X + ((size_t)(b * 3 + co) << 16);
        float x = Xc[(h << 8) + wc];
        float res;
        if (x == 0.f) {
            float lft = (wc > 0)   ? Xc[(h << 8) + wc - 1] : 0.f;
            float rgt = (wc < 255) ? Xc[(h << 8) + wc + 1] : 0.f;
            float top = (h > 0)    ? Xc[((h - 1) << 8) + wc] : 0.f;
            float bot = (h < 255)  ? Xc[((h + 1) << 8) + wc] : 0.f;
            float s = lft + rgt + top + bot;
            int cnt = (lft > 0.f) + (rgt > 0.f) + (top > 0.f) + (bot > 0.f);
            res = cnt > 0 ? s / (float)cnt : 0.f;
        } else {
            res = x;
        }
        out[((b * 3 + co) << 16) + (h << 8) + wc] = val + res;
    }
}

extern "C" void kernel_launch(void* const* d_in, const int* in_sizes, int n_in,
                              void* d_out, int out_size, void* d_ws, size_t ws_size,
                              hipStream_t stream) {
    (void)in_sizes; (void)n_in; (void)out_size; (void)ws_size;
    const float* X    = (const float*)d_in[0];
    const float* w_in = (const float*)d_in[1];
    const float* b_in = (const float*)d_in[2];
    const float* g_in = (const float*)d_in[3];
    const float* be_in= (const float*)d_in[4];
    const float* m_in = (const float*)d_in[5];
    const float* v_in = (const float*)d_in[6];
    const float* w_h  = (const float*)d_in[7];
    const float* b_h  = (const float*)d_in[8];
    const float* g_h  = (const float*)d_in[9];
    const float* be_h = (const float*)d_in[10];
    const float* m_h  = (const float*)d_in[11];
    const float* v_h  = (const float*)d_in[12];
    const float* w_o  = (const float*)d_in[13];
    const float* b_o  = (const float*)d_in[14];
    const float* g_o  = (const float*)d_in[15];
    const float* be_o = (const float*)d_in[16];
    const float* m_o  = (const float*)d_in[17];
    const float* v_o  = (const float*)d_in[18];
    float* out = (float*)d_out;

    // fp32 ping-pong activation buffers: 2 x 4*64*256*256 floats = 134.2 MB
    float* buf0 = (float*)d_ws;
    float* buf1 = buf0 + (size_t)BATCH * NCC * HH * WW;

    dim3 grid(WW / 16, HH / 16, BATCH), block(256);
    k_conv_in<<<grid, block, 0, stream>>>(X, w_in, b_in, g_in, be_in, m_in, v_in, buf0);
    float* src = buf0;
    float* dst = buf1;
    for (int i = 0; i < 18; ++i) {
        k_hidden<<<grid, block, 0, stream>>>(src, w_h, b_h, g_h, be_h, m_h, v_h, dst);
        float* t = src; src = dst; dst = t;
    }
    k_conv_out<<<grid, block, 0, stream>>>(src, w_o, b_o, g_o, be_o, m_o, v_o, X, out);
}

// Round 3
// 701.060 us; speedup vs baseline: 7.9348x; 7.9348x over previous
//
#include <hip/hip_runtime.h>

#define EPS 1e-5f
#define SELU_L 1.0507009873554805f
#define SELU_A 1.6732632423543772f
#define SELU_LA (SELU_L * SELU_A)

typedef _Float16 half8 __attribute__((ext_vector_type(8)));
typedef _Float16 half4 __attribute__((ext_vector_type(4)));
typedef float floatx4 __attribute__((ext_vector_type(4)));

__device__ __forceinline__ float selu_f(float x) {
    return x > 0.f ? SELU_L * x : SELU_LA * (__expf(x) - 1.f);
}

// ------------- weight swizzle prep: A-operand fragment order, fp16 -------------
// wb_h : [t=18][mi=4][L=64][j=8]  co = mi*16 + (L&15), ci = (t&1)*32 + (L>>4)*8 + j, s = t>>1
// wb_in: [mi=4][L=64][j=8]        k = (L>>4)*8+j -> s=k/3, ci=k%3 (k>=27 -> 0)
// wb_out:[t=18][L=64][j=8]        co = L&15 (valid <3), ci/s as wb_h
__global__ __launch_bounds__(256) void k_prep(
    const float* __restrict__ w_h, const float* __restrict__ w_in,
    const float* __restrict__ w_out, _Float16* __restrict__ wb_h,
    _Float16* __restrict__ wb_in, _Float16* __restrict__ wb_out)
{
    int i = blockIdx.x * 256 + threadIdx.x;
    if (i < 36864) {
        int t = i >> 11;
        int rem = i & 2047;
        int mi = rem >> 9;
        int L = (rem >> 3) & 63;
        int j = i & 7;
        int co = mi * 16 + (L & 15);
        int ci = ((t & 1) << 5) + ((L >> 4) << 3) + j;
        int s = t >> 1;
        wb_h[i] = (_Float16)w_h[(co * 64 + ci) * 9 + s];
    } else if (i < 36864 + 2048) {
        int e = i - 36864;
        int mi = e >> 9;
        int L = (e >> 3) & 63;
        int j = e & 7;
        int co = mi * 16 + (L & 15);
        int k = ((L >> 4) << 3) + j;
        _Float16 val = (_Float16)0.f;
        if (k < 27) {
            int s = k / 3, ci = k - s * 3;
            val = (_Float16)w_in[(co * 3 + ci) * 9 + s];
        }
        wb_in[e] = val;
    } else if (i < 36864 + 2048 + 9216) {
        int e = i - 36864 - 2048;
        int t = e >> 9;
        int L = (e >> 3) & 63;
        int j = e & 7;
        int co = L & 15;
        int ci = ((t & 1) << 5) + ((L >> 4) << 3) + j;
        int s = t >> 1;
        _Float16 val = (_Float16)0.f;
        if (co < 3) val = (_Float16)w_out[(co * 64 + ci) * 9 + s];
        wb_out[e] = val;
    }
}

// ------------- conv_in: 3 -> 64, BN, SELU, NHWC fp16 out (MFMA, K=32) -------------
__global__ __launch_bounds__(256) void k_conv_in_mfma(
    const float* __restrict__ X, const _Float16* __restrict__ wb,
    const float* __restrict__ bconv, const float* __restrict__ g,
    const float* __restrict__ be, const float* __restrict__ bm,
    const float* __restrict__ bv, _Float16* __restrict__ dst)
{
    __shared__ float s_x[3][18][18];
    __shared__ float s_sc[64], s_bs[64];
    const int tid = threadIdx.x;
    const int w0 = blockIdx.x * 16, h0 = blockIdx.y * 16, b = blockIdx.z;

    if (tid < 64) {
        float sc = g[tid] * rsqrtf(bv[tid] + EPS);
        s_sc[tid] = sc;
        s_bs[tid] = (bconv[tid] - bm[tid]) * sc + be[tid];
    }
    for (int idx = tid; idx < 3 * 324; idx += 256) {
        int ci = idx / 324, rem = idx - ci * 324;
        int r = rem / 18, c = rem - r * 18;
        int gh = h0 - 1 + r, gw = w0 - 1 + c;
        float val = 0.f;
        if ((unsigned)gh < 256u && (unsigned)gw < 256u)
            val = X[((b * 3 + ci) << 16) + (gh << 8) + gw];
        s_x[ci][r][c] = val;
    }
    __syncthreads();

    const int wv = tid >> 6, L = tid & 63, quad = L >> 4, l15 = L & 15;
    half8 a[4];
    #pragma unroll
    for (int mi = 0; mi < 4; ++mi)
        a[mi] = *(const half8*)(wb + (mi * 64 + L) * 8);

    floatx4 acc[4][4];
    #pragma unroll
    for (int mi = 0; mi < 4; ++mi)
        #pragma unroll
        for (int ni = 0; ni < 4; ++ni) acc[mi][ni] = (floatx4){0.f, 0.f, 0.f, 0.f};

    #pragma unroll
    for (int ni = 0; ni < 4; ++ni) {
        half8 bfr;
        #pragma unroll
        for (int j = 0; j < 8; ++j) {
            int k = quad * 8 + j;
            float xv = 0.f;
            if (k < 27) {
                int s = k / 3, ci = k - s * 3;
                int kh = s / 3, kw = s - kh * 3;
                xv = s_x[ci][wv * 4 + ni + kh][l15 + kw];
            }
            bfr[j] = (_Float16)xv;
        }
        #pragma unroll
        for (int mi = 0; mi < 4; ++mi)
            acc[mi][ni] = __builtin_amdgcn_mfma_f32_16x16x32_f16(a[mi], bfr, acc[mi][ni], 0, 0, 0);
    }

    _Float16* db = dst + ((size_t)b << 22);  // b*256*256*64
    #pragma unroll
    for (int mi = 0; mi < 4; ++mi) {
        const int cob = mi * 16 + quad * 4;
        floatx4 sc = *(const floatx4*)(&s_sc[cob]);
        floatx4 bs = *(const floatx4*)(&s_bs[cob]);
        #pragma unroll
        for (int ni = 0; ni < 4; ++ni) {
            half4 ov;
            #pragma unroll
            for (int r = 0; r < 4; ++r)
                ov[r] = (_Float16)selu_f(acc[mi][ni][r] * sc[r] + bs[r]);
            const int row = h0 + wv * 4 + ni, col = w0 + l15;
            *(half4*)(db + ((((row << 8) + col) << 6) + cob)) = ov;
        }
    }
}

// ------------- hidden: 64 -> 64, BN, SELU (MFMA implicit GEMM, K=576) -------------
__global__ __launch_bounds__(256) void k_hidden_mfma(
    const _Float16* __restrict__ src, const _Float16* __restrict__ wb,
    const float* __restrict__ bconv, const float* __restrict__ g,
    const float* __restrict__ be, const float* __restrict__ bm,
    const float* __restrict__ bv, _Float16* __restrict__ dst)
{
    __shared__ _Float16 s_in[324 * 72];  // [pixel=row*18+col][64 ci + 8 pad]
    __shared__ float s_sc[64], s_bs[64];
    const int tid = threadIdx.x;
    const int w0 = blockIdx.x * 16, h0 = blockIdx.y * 16, b = blockIdx.z;
    const _Float16* sb = src + ((size_t)b << 22);

    if (tid < 64) {
        float sc = g[tid] * rsqrtf(bv[tid] + EPS);
        s_sc[tid] = sc;
        s_bs[tid] = (bconv[tid] - bm[tid]) * sc + be[tid];
    }
    // stage 18x18x64 fp16 halo tile, 16B chunks, fully coalesced (NHWC)
    for (int idx = tid; idx < 2592; idx += 256) {
        int r = idx / 144, cpos = idx - r * 144;
        int col = cpos >> 3, sub = cpos & 7;
        int gh = h0 - 1 + r, gw = w0 - 1 + col;
        half8 val = {0, 0, 0, 0, 0, 0, 0, 0};
        if ((unsigned)gh < 256u && (unsigned)gw < 256u)
            val = *(const half8*)(sb + ((((gh << 8) + gw) << 6) + (sub << 3)));
        *(half8*)(&s_in[(r * 18 + col) * 72 + (sub << 3)]) = val;
    }
    __syncthreads();

    const int wv = tid >> 6, L = tid & 63, quad = L >> 4, l15 = L & 15;
    floatx4 acc[4][4];
    #pragma unroll
    for (int mi = 0; mi < 4; ++mi)
        #pragma unroll
        for (int ni = 0; ni < 4; ++ni) acc[mi][ni] = (floatx4){0.f, 0.f, 0.f, 0.f};

    #pragma unroll
    for (int t = 0; t < 18; ++t) {
        const int s = t >> 1, ci0 = (t & 1) << 5;
        const int kh = s / 3, kw = s - kh * 3;
        half8 a[4];
        #pragma unroll
        for (int mi = 0; mi < 4; ++mi)
            a[mi] = *(const half8*)(wb + ((t * 4 + mi) * 64 + L) * 8);
        #pragma unroll
        for (int ni = 0; ni < 4; ++ni) {
            const int row = wv * 4 + ni + kh, col = l15 + kw;
            half8 bfr = *(const half8*)(&s_in[(row * 18 + col) * 72 + ci0 + quad * 8]);
            #pragma unroll
            for (int mi = 0; mi < 4; ++mi)
                acc[mi][ni] = __builtin_amdgcn_mfma_f32_16x16x32_f16(a[mi], bfr, acc[mi][ni], 0, 0, 0);
        }
    }

    _Float16* db = dst + ((size_t)b << 22);
    #pragma unroll
    for (int mi = 0; mi < 4; ++mi) {
        const int cob = mi * 16 + quad * 4;
        floatx4 sc = *(const floatx4*)(&s_sc[cob]);
        floatx4 bs = *(const floatx4*)(&s_bs[cob]);
        #pragma unroll
        for (int ni = 0; ni < 4; ++ni) {
            half4 ov;
            #pragma unroll
            for (int r = 0; r < 4; ++r)
                ov[r] = (_Float16)selu_f(acc[mi][ni][r] * sc[r] + bs[r]);
            const int row = h0 + wv * 4 + ni, col = w0 + l15;
            *(half4*)(db + ((((row << 8) + col) << 6) + cob)) = ov;
        }
    }
}

// ------------- conv_out: 64 -> 3, BN, SELU, + interpolate_zeros(X), fp32 out -------------
__global__ __launch_bounds__(256) void k_conv_out_mfma(
    const _Float16* __restrict__ src, const _Float16* __restrict__ wb,
    const float* __restrict__ bconv, const float* __restrict__ g,
    const float* __restrict__ be, const float* __restrict__ bm,
    const float* __restrict__ bv, const float* __restrict__ X,
    float* __restrict__ out)
{
    __shared__ _Float16 s_in[324 * 72];
    const int tid = threadIdx.x;
    const int w0 = blockIdx.x * 16, h0 = blockIdx.y * 16, b = blockIdx.z;
    const _Float16* sb = src + ((size_t)b << 22);

    for (int idx = tid; idx < 2592; idx += 256) {
        int r = idx / 144, cpos = idx - r * 144;
        int col = cpos >> 3, sub = cpos & 7;
        int gh = h0 - 1 + r, gw = w0 - 1 + col;
        half8 val = {0, 0, 0, 0, 0, 0, 0, 0};
        if ((unsigned)gh < 256u && (unsigned)gw < 256u)
            val = *(const half8*)(sb + ((((gh << 8) + gw) << 6) + (sub << 3)));
        *(half8*)(&s_in[(r * 18 + col) * 72 + (sub << 3)]) = val;
    }
    __syncthreads();

    const int wv = tid >> 6, L = tid & 63, quad = L >> 4, l15 = L & 15;
    floatx4 acc[4];
    #pragma unroll
    for (int ni = 0; ni < 4; ++ni) acc[ni] = (floatx4){0.f, 0.f, 0.f, 0.f};

    #pragma unroll
    for (int t = 0; t < 18; ++t) {
        const int s = t >> 1, ci0 = (t & 1) << 5;
        const int kh = s / 3, kw = s - kh * 3;
        half8 a = *(const half8*)(wb + (t * 64 + L) * 8);
        #pragma unroll
        for (int ni = 0; ni < 4; ++ni) {
            const int row = wv * 4 + ni + kh, col = l15 + kw;
            half8 bfr = *(const half8*)(&s_in[(row * 18 + col) * 72 + ci0 + quad * 8]);
            acc[ni] = __builtin_amdgcn_mfma_f32_16x16x32_f16(a, bfr, acc[ni], 0, 0, 0);
        }
    }

    if (quad == 0) {
        float sc[3], bs[3];
        #pragma unroll
        for (int co = 0; co < 3; ++co) {
            sc[co] = g[co] * rsqrtf(bv[co] + EPS);
            bs[co] = (bconv[co] - bm[co]) * sc[co] + be[co];
        }
        #pragma unroll
        for (int ni = 0; ni < 4; ++ni) {
            const int h = h0 + wv * 4 + ni, wc = w0 + l15;
            #pragma unroll
            for (int co = 0; co < 3; ++co) {
                float val = selu_f(acc[ni][co] * sc[co] + bs[co]);
                const float* Xc = X + ((size_t)(b * 3 + co) << 16);
                float x = Xc[(h << 8) + wc];
                float res;
                if (x == 0.f) {
                    float lft = (wc > 0)   ? Xc[(h << 8) + wc - 1] : 0.f;
                    float rgt = (wc < 255) ? Xc[(h << 8) + wc + 1] : 0.f;
                    float top = (h > 0)    ? Xc[((h - 1) << 8) + wc] : 0.f;
                    float bot = (h < 255)  ? Xc[((h + 1) << 8) + wc] : 0.f;
                    float sm = lft + rgt + top + bot;
                    int cnt = (lft > 0.f) + (rgt > 0.f) + (top > 0.f) + (bot > 0.f);
                    res = cnt > 0 ? sm / (float)cnt : 0.f;
                } else {
                    res = x;
                }
                out[((b * 3 + co) << 16) + (h << 8) + wc] = val + res;
            }
        }
    }
}

extern "C" void kernel_launch(void* const* d_in, const int* in_sizes, int n_in,
                              void* d_out, int out_size, void* d_ws, size_t ws_size,
                              hipStream_t stream) {
    (void)in_sizes; (void)n_in; (void)out_size; (void)ws_size;
    const float* X    = (const float*)d_in[0];
    const float* w_in = (const float*)d_in[1];
    const float* b_in = (const float*)d_in[2];
    const float* g_in = (const float*)d_in[3];
    const float* be_in= (const float*)d_in[4];
    const float* m_in = (const float*)d_in[5];
    const float* v_in = (const float*)d_in[6];
    const float* w_h  = (const float*)d_in[7];
    const float* b_h  = (const float*)d_in[8];
    const float* g_h  = (const float*)d_in[9];
    const float* be_h = (const float*)d_in[10];
    const float* m_h  = (const float*)d_in[11];
    const float* v_h  = (const float*)d_in[12];
    const float* w_o  = (const float*)d_in[13];
    const float* b_o  = (const float*)d_in[14];
    const float* g_o  = (const float*)d_in[15];
    const float* be_o = (const float*)d_in[16];
    const float* m_o  = (const float*)d_in[17];
    const float* v_o  = (const float*)d_in[18];
    float* out = (float*)d_out;

    // ws layout (fp16 elems): act0[16.78M] act1[16.78M] wb_h[36864] wb_in[2048] wb_out[9216]
    _Float16* act0  = (_Float16*)d_ws;
    _Float16* act1  = act0 + ((size_t)1 << 24);
    _Float16* wb_h  = act1 + ((size_t)1 << 24);
    _Float16* wb_in = wb_h + 36864;
    _Float16* wb_out= wb_in + 2048;

    dim3 grid(16, 16, 4), block(256);
    k_prep<<<188, 256, 0, stream>>>(w_h, w_in, w_o, wb_h, wb_in, wb_out);
    k_conv_in_mfma<<<grid, block, 0, stream>>>(X, wb_in, b_in, g_in, be_in, m_in, v_in, act0);
    _Float16* src = act0;
    _Float16* dst = act1;
    for (int i = 0; i < 18; ++i) {
        k_hidden_mfma<<<grid, block, 0, stream>>>(src, wb_h, b_h, g_h, be_h, m_h, v_h, dst);
        _Float16* t = src; src = dst; dst = t;
    }
    k_conv_out_mfma<<<grid, block, 0, stream>>>(src, wb_out, b_o, g_o, be_o, m_o, v_o, X, out);
}